// Round 3
// baseline (193.437 us; speedup 1.0000x reference)
//
#include <hip/hip_runtime.h>
#include <hip/hip_bf16.h>

// Per-neuron MLP. D=2048 neurons: [B=256,M=32]@W0[32,64] -> gelu -> @W1[64,64]
// -> gelu -> @W2[64,1] -> out[B,D].
//
// Dtype model after R1/R2 forensics:
//  - OUTPUT is FP32 (reference output dtype; R2's u16-packed bf16 writes read
//    back as fp32 gave exactly the observed ~1.8e-5 decorrelated-garbage error).
//  - INPUTS are fp32 per the reference (R1 all-bf16 read -> NaN = fp32 bits as
//    bf16), but we hedge with an in-kernel storage-dtype detector per tensor:
//    packed-bf16 arrays have concentrated exponent bits in the LOW short of
//    each u32; fp32 arrays have uniform mantissa bits there. 64 samples,
//    threshold 40/64 -> ~1e-6 misdetect probability. fp32-values-rounded-to-
//    bf16 correctly classify as "read fp32".
//
// Structure: 1 workgroup per d. 256 threads = 4 waves; wave w owns rows
// [64w,64w+64) (4 row-tiles of 16). No barriers in the main loop (per-wave LDS
// h scratch + explicit lgkmcnt fences). MFMA bf16 16x16x32, fp32 accum;
// W2/biases fp32. bf16-rounding of X,W0,W1,h costs ~2.5e-8 max abs err vs
// 3.05e-7 threshold.

typedef short bf16x8 __attribute__((ext_vector_type(8)));
typedef short short4v __attribute__((ext_vector_type(4)));
typedef short short8v __attribute__((ext_vector_type(8)));
typedef float f32x4 __attribute__((ext_vector_type(4)));

#define D_DIM 2048
#define M_DIM 32
#define H_DIM 64
#define B_DIM 256

// LDS row strides (shorts): 16B-aligned rows, <=2-way bank aliasing (free)
#define XS  40
#define W0S 40
#define W1S 72
#define HS  72

__device__ __forceinline__ short f2bf(float f) {
    union { float f; unsigned u; } cv; cv.f = f;
    unsigned u = cv.u;
    u += 0x7FFFu + ((u >> 16) & 1u);   // RNE
    return (short)(u >> 16);
}

__device__ __forceinline__ float bfbits2f(unsigned short s) {
    union { unsigned u; float f; } cv;
    cv.u = ((unsigned)s) << 16;
    return cv.f;
}

// exact (erf) GELU; pre-acts are tiny (|x| <~ 0.1), Maclaurin accurate ~1e-9.
__device__ __forceinline__ float gelu_exact(float x) {
    float s = x * x;
    if (__builtin_expect(s > 0.25f, 0)) {
        return 0.5f * x * (1.0f + erff(x * 0.70710678118654752f));
    }
    float q = fmaf(s, fmaf(s, fmaf(s, -1.1873287e-3f, 9.9735570e-3f),
                           -6.6490380e-2f), 3.9894228e-1f);
    return fmaf(s, q, 0.5f * x);
}

// True if the array at p is packed u16 bf16 (vs genuine fp32).
// Looks at exponent field of the LOW short of 64 consecutive u32 words.
__device__ __forceinline__ bool looks_packed_bf16(const unsigned* __restrict__ p) {
    int cnt = 0;
    #pragma unroll 8
    for (int i = 0; i < 64; ++i) {
        unsigned e = (p[i] >> 7) & 0xFFu;   // bits 14:7 of low short
        cnt += (e >= 0x50u && e <= 0x8Au) ? 1 : 0;
    }
    return cnt >= 40;
}

__global__ __launch_bounds__(256) void neuron_mlp_kernel(
    const void* __restrict__ histp,  // [B, D, M]
    const void* __restrict__ W0p,    // [D, M, H]
    const void* __restrict__ b0p,    // [D, H]
    const void* __restrict__ W1p,    // [D, H, H]
    const void* __restrict__ b1p,    // [D, H]
    const void* __restrict__ W2p,    // [D, H]
    const void* __restrict__ b2p,    // [D]
    float* __restrict__ out)         // [B, D] fp32
{
    __shared__ __align__(16) short lds_x[B_DIM * XS];     // 20480 B
    __shared__ __align__(16) short lds_w0[H_DIM * W0S];   // 5120 B  ([h][m])
    __shared__ __align__(16) short lds_w1[H_DIM * W1S];   // 9216 B  ([o][k])
    __shared__ __align__(16) short lds_h[4][16 * HS];     // 9216 B  per-wave
    __shared__ float lds_b0[H_DIM];
    __shared__ float lds_b1[H_DIM];
    __shared__ float lds_w2[H_DIM];
    __shared__ float lds_b2;

    const int t = threadIdx.x;
    const int bid = blockIdx.x;
    // XCD swizzle: consecutive d land on the same XCD (L2 line sharing)
    const int d = ((bid & 7) << 8) | (bid >> 3);

    // ---- storage-dtype detection (wave-uniform scalar loads) ----
    const bool hist_bf = looks_packed_bf16((const unsigned*)histp);
    const bool w0_bf   = looks_packed_bf16((const unsigned*)W0p);
    const bool w1_bf   = looks_packed_bf16((const unsigned*)W1p);
    const bool w2_bf   = looks_packed_bf16((const unsigned*)W2p);

    // ---- stage X[256,32] -> bf16 LDS ----
    if (!hist_bf) {
        const float* hist = (const float*)histp;
        const int chunk = t & 7, rbase = t >> 3;
        #pragma unroll
        for (int it = 0; it < 8; ++it) {
            const int row = it * 32 + rbase;
            f32x4 v = *(const f32x4*)&hist[(size_t)row * (D_DIM * M_DIM)
                                           + (size_t)d * M_DIM + chunk * 4];
            short4v bv;
            #pragma unroll
            for (int j = 0; j < 4; ++j) bv[j] = f2bf(v[j]);
            *(short4v*)&lds_x[row * XS + chunk * 4] = bv;
        }
    } else {
        const short* hist = (const short*)histp;
        const int chunk = t & 3, rbase = t >> 2;
        #pragma unroll
        for (int it = 0; it < 4; ++it) {
            const int row = it * 64 + rbase;
            short8v v = *(const short8v*)&hist[(size_t)row * (D_DIM * M_DIM)
                                               + (size_t)d * M_DIM + chunk * 8];
            *(short8v*)&lds_x[row * XS + chunk * 8] = v;
        }
    }
    // ---- stage W0 transposed: lds_w0[h][m] ----
    if (!w0_bf) {
        const float* W0 = (const float*)W0p;
        #pragma unroll
        for (int i = 0; i < 2; ++i) {
            const int flat = i * 1024 + t * 4;
            f32x4 v = *(const f32x4*)&W0[(size_t)d * (M_DIM * H_DIM) + flat];
            const int m = flat >> 6, h = flat & 63;
            #pragma unroll
            for (int j = 0; j < 4; ++j) lds_w0[(h + j) * W0S + m] = f2bf(v[j]);
        }
    } else {
        const short* W0 = (const short*)W0p;
        const int flat = t * 8;
        short8v v = *(const short8v*)&W0[(size_t)d * (M_DIM * H_DIM) + flat];
        const int m = flat >> 6, h = flat & 63;
        #pragma unroll
        for (int j = 0; j < 8; ++j) lds_w0[(h + j) * W0S + m] = v[j];
    }
    // ---- stage W1 transposed: lds_w1[o][k] ----
    if (!w1_bf) {
        const float* W1 = (const float*)W1p;
        #pragma unroll
        for (int i = 0; i < 4; ++i) {
            const int flat = i * 1024 + t * 4;
            f32x4 v = *(const f32x4*)&W1[(size_t)d * (H_DIM * H_DIM) + flat];
            const int k = flat >> 6, o = flat & 63;
            #pragma unroll
            for (int j = 0; j < 4; ++j) lds_w1[(o + j) * W1S + k] = f2bf(v[j]);
        }
    } else {
        const short* W1 = (const short*)W1p;
        #pragma unroll
        for (int i = 0; i < 2; ++i) {
            const int flat = i * 2048 + t * 8;
            short8v v = *(const short8v*)&W1[(size_t)d * (H_DIM * H_DIM) + flat];
            const int k = flat >> 6, o = flat & 63;
            #pragma unroll
            for (int j = 0; j < 8; ++j) lds_w1[(o + j) * W1S + k] = v[j];
        }
    }
    // ---- biases / W2 as fp32 (biases are zeros -> dtype-invariant, but
    //      follow W2's verdict anyway) ----
    if (t < H_DIM) {
        if (!w2_bf) {
            lds_b0[t] = ((const float*)b0p)[d * H_DIM + t];
            lds_b1[t] = ((const float*)b1p)[d * H_DIM + t];
            lds_w2[t] = ((const float*)W2p)[d * H_DIM + t];
        } else {
            lds_b0[t] = bfbits2f(((const unsigned short*)b0p)[d * H_DIM + t]);
            lds_b1[t] = bfbits2f(((const unsigned short*)b1p)[d * H_DIM + t]);
            lds_w2[t] = bfbits2f(((const unsigned short*)W2p)[d * H_DIM + t]);
        }
    }
    if (t == 0) {
        lds_b2 = w2_bf ? bfbits2f(((const unsigned short*)b2p)[d])
                       : ((const float*)b2p)[d];
    }

    __syncthreads();

    const int w = t >> 6;
    const int l = t & 63;
    const int row16 = l & 15;   // MFMA A-row / B-col / D-col lane index
    const int quad = l >> 4;    // MFMA k-group / D-row group

    // hoist B fragments (invariant over row-tiles); 16B-aligned LDS reads
    bf16x8 bw0[4];
    bf16x8 bw1[4][2];
    float b0v[4], b1v[4], w2v[4];
    #pragma unroll
    for (int n = 0; n < 4; ++n) {
        const int o = n * 16 + row16;
        bw0[n]    = *(bf16x8*)&lds_w0[o * W0S + quad * 8];
        bw1[n][0] = *(bf16x8*)&lds_w1[o * W1S + quad * 8];
        bw1[n][1] = *(bf16x8*)&lds_w1[o * W1S + 32 + quad * 8];
        b0v[n] = lds_b0[o];
        b1v[n] = lds_b1[o];
        w2v[n] = lds_w2[o];
    }
    const float b2v = lds_b2;
    const f32x4 zf = {0.f, 0.f, 0.f, 0.f};
    short* hbuf = lds_h[w];

    #pragma unroll
    for (int rt = 0; rt < 4; ++rt) {
        const int base_row = w * 64 + rt * 16;

        // ---- layer 0: [16,32] @ [32,64], K=32 in one MFMA per col-tile ----
        bf16x8 a0 = *(bf16x8*)&lds_x[(base_row + row16) * XS + quad * 8];
        f32x4 acc0[4];
        #pragma unroll
        for (int n = 0; n < 4; ++n)
            acc0[n] = __builtin_amdgcn_mfma_f32_16x16x32_bf16(a0, bw0[n], zf, 0, 0, 0);

        // bias + gelu -> bf16 h tile in per-wave LDS
        // (D layout: row=quad*4+r, col=n*16+row16)
        #pragma unroll
        for (int n = 0; n < 4; ++n) {
            #pragma unroll
            for (int r = 0; r < 4; ++r) {
                float hval = gelu_exact(acc0[n][r] + b0v[n]);
                hbuf[(quad * 4 + r) * HS + n * 16 + row16] = f2bf(hval);
            }
        }
        // wave-internal LDS write->read ordering fence
        asm volatile("s_waitcnt lgkmcnt(0)" ::: "memory");

        // ---- layer 1: [16,64] @ [64,64], K=64 = 2 MFMAs per col-tile ----
        bf16x8 a1_0 = *(bf16x8*)&hbuf[row16 * HS + quad * 8];
        bf16x8 a1_1 = *(bf16x8*)&hbuf[row16 * HS + 32 + quad * 8];
        asm volatile("s_waitcnt lgkmcnt(0)" ::: "memory");
        float p[4] = {0.f, 0.f, 0.f, 0.f};
        #pragma unroll
        for (int n = 0; n < 4; ++n) {
            f32x4 acc1 = __builtin_amdgcn_mfma_f32_16x16x32_bf16(a1_0, bw1[n][0], zf, 0, 0, 0);
            acc1 = __builtin_amdgcn_mfma_f32_16x16x32_bf16(a1_1, bw1[n][1], acc1, 0, 0, 0);
            #pragma unroll
            for (int r = 0; r < 4; ++r) {
                float h2 = gelu_exact(acc1[r] + b1v[n]);
                p[r] = fmaf(h2, w2v[n], p[r]);   // layer-2 partial dot
            }
        }

        // ---- layer 2 finish: reduce over the 16 lanes of each quad ----
        #pragma unroll
        for (int r = 0; r < 4; ++r) {
            #pragma unroll
            for (int off = 1; off < 16; off <<= 1)
                p[r] += __shfl_xor(p[r], off, 64);
        }
        if (row16 == 0) {
            #pragma unroll
            for (int r = 0; r < 4; ++r) {
                const int b = base_row + quad * 4 + r;
                out[(size_t)b * D_DIM + d] = p[r] + b2v;   // fp32 store
            }
        }
    }
}

extern "C" void kernel_launch(void* const* d_in, const int* in_sizes, int n_in,
                              void* d_out, int out_size, void* d_ws, size_t ws_size,
                              hipStream_t stream) {
    neuron_mlp_kernel<<<dim3(D_DIM), dim3(256), 0, stream>>>(
        d_in[0], d_in[1], d_in[2], d_in[3], d_in[4], d_in[5], d_in[6],
        (float*)d_out);
}